// Round 7
// baseline (463.340 us; speedup 1.0000x reference)
//
#include <hip/hip_runtime.h>
#include <hip/hip_bf16.h>

typedef unsigned short u16;
typedef unsigned int u32;
typedef long long i64;
typedef __attribute__((ext_vector_type(8))) short s8v;    // 8 bf16 (4 VGPRs)
typedef __attribute__((ext_vector_type(4))) float f32x4;  // MFMA acc

__device__ __forceinline__ float bf2f(u16 u) {
    union { u32 i; float f; } x; x.i = ((u32)u) << 16; return x.f;
}
__device__ __forceinline__ u16 f2bf(float f) {
    union { float f; u32 i; } x; x.f = f;
    u32 v = x.i;
    u32 r = v + 0x7FFFu + ((v >> 16) & 1u);   // RNE
    return (u16)(r >> 16);
}
__device__ __forceinline__ float get_f(const void* p, size_t i, int fp32) {
    return fp32 ? ((const float*)p)[i] : bf2f(((const u16*)p)[i]);
}
__device__ __forceinline__ int get_i(const void* p, size_t i, int m64) {
    return m64 ? (int)((const i64*)p)[i] : ((const int*)p)[i];
}
__device__ __forceinline__ float lrelu_clamp(float v) {
    v = v > 0.f ? v : 0.2f * v;
    return fminf(v, 80.f);
}

// ---------------------------------------------------------------------------
// k_init: block 0 = dtype detect; blocks 1..64 = W transpose (bf16 path);
// all blocks stride-zero cnt[].
// ---------------------------------------------------------------------------
__global__ __launch_bounds__(256) void k_init(
    const u16* __restrict__ hin, const int* __restrict__ eidx, int* __restrict__ flags,
    const u16* __restrict__ W, u16* __restrict__ Wt, int* __restrict__ cnt, int n_nodes)
{
    const int b = blockIdx.x, t = threadIdx.x;
    if (b == 0) {
        __shared__ int c1, c2;
        if (t == 0) { c1 = 0; c2 = 0; }
        __syncthreads();
        int l1 = 0, l2 = 0;
        for (int i = t; i < 8192; i += 256) {
            float v = bf2f(hin[i]);
            if (!(fabsf(v) <= 100.f)) l1++;
            if ((i & 1) && eidx[i] == 0) l2++;
        }
        atomicAdd(&c1, l1); atomicAdd(&c2, l2);
        __syncthreads();
        if (t == 0) {
            flags[0] = (c1 > 40) ? 1 : 0;
            flags[1] = (c2 > 3000) ? 1 : 0;
        }
    } else {
        int i = (b - 1) * 256 + t;
        int k = i >> 7, n = i & 127;
        Wt[(size_t)n * 128 + k] = W[(size_t)k * 128 + n];
    }
    for (int i = b * 256 + t; i < n_nodes; i += gridDim.x * 256) cnt[i] = 0;
}

// ---------------------------------------------------------------------------
// Projection (both modes) + fused score tables.
// bf16 mode: MFMA, wave = 16 rows x 128 cols, hp PERMUTED
//   (hp[row*128 + col*8 + ct] = h_proj[row][ct*16+col]), grid blocks >= ceil(M/64).
// fp32 mode: vector 32-rows/block path, hp un-permuted fp32.
// ---------------------------------------------------------------------------
__global__ __launch_bounds__(256) void k_proj(
    const void* __restrict__ hin_, const void* __restrict__ W_,
    const u16* __restrict__ Wt, const void* __restrict__ bias_,
    const void* __restrict__ a_src_, const void* __restrict__ a_tgt_,
    const int* __restrict__ flags, void* __restrict__ hp_,
    float* __restrict__ ssrc, float* __restrict__ stgt, int M)
{
    __shared__ float hs[32][128];
    __shared__ float sh_s[32][4], sh_t[32][4];
    const int fp32 = flags[0];

    if (!fp32) {
        // ---------------- MFMA path ----------------
        const u16* hin = (const u16*)hin_;
        const u16* bias = (const u16*)bias_;
        const u16* a_src = (const u16*)a_src_;
        const u16* a_tgt = (const u16*)a_tgt_;
        u16* hp = (u16*)hp_;
        const int wave = threadIdx.x >> 6;
        const int lane = threadIdx.x & 63;
        const int q = lane >> 4, col = lane & 15;
        const int row0 = blockIdx.x * 64 + wave * 16;
        if (row0 >= M) return;

        const int arow = min(row0 + col, M - 1);
        f32x4 acc[8];
        #pragma unroll
        for (int ct = 0; ct < 8; ct++) acc[ct] = (f32x4){0.f, 0.f, 0.f, 0.f};

        #pragma unroll
        for (int kc = 0; kc < 4; kc++) {
            s8v afrag = *(const s8v*)(hin + (size_t)arow * 128 + kc * 32 + q * 8);
            #pragma unroll
            for (int ct = 0; ct < 8; ct++) {
                s8v bfrag = *(const s8v*)(Wt + (size_t)(ct * 16 + col) * 128 + kc * 32 + q * 8);
                acc[ct] = __builtin_amdgcn_mfma_f32_16x16x32_bf16(afrag, bfrag, acc[ct], 0, 0, 0);
            }
        }

        float bb[8], as[8], at[8];
        #pragma unroll
        for (int ct = 0; ct < 8; ct++) {
            int c = ct * 16 + col;
            bb[ct] = bf2f(bias[c]);
            as[ct] = bf2f(a_src[c]);
            at[ct] = bf2f(a_tgt[c]);
        }

        #pragma unroll
        for (int r = 0; r < 4; r++) {
            int row = row0 + q * 4 + r;
            float ps0 = 0.f, ps1 = 0.f, ps2 = 0.f, ps3 = 0.f;
            float pt0 = 0.f, pt1 = 0.f, pt2 = 0.f, pt3 = 0.f;
            float ov[8];
            #pragma unroll
            for (int ct = 0; ct < 8; ct++) {
                float v = acc[ct][r] + bb[ct];
                ov[ct] = v;
                float s = v * as[ct], t2 = v * at[ct];
                if (ct < 2)      { ps0 += s; pt0 += t2; }
                else if (ct < 4) { ps1 += s; pt1 += t2; }
                else if (ct < 6) { ps2 += s; pt2 += t2; }
                else             { ps3 += s; pt3 += t2; }
            }
            if (row < M) {
                union { ushort4 h[2]; uint4 qv; } pk;
                pk.h[0] = make_ushort4(f2bf(ov[0]), f2bf(ov[1]), f2bf(ov[2]), f2bf(ov[3]));
                pk.h[1] = make_ushort4(f2bf(ov[4]), f2bf(ov[5]), f2bf(ov[6]), f2bf(ov[7]));
                *(uint4*)(hp + (size_t)row * 128 + col * 8) = pk.qv;
            }
            #pragma unroll
            for (int m = 1; m < 16; m <<= 1) {
                ps0 += __shfl_xor(ps0, m); ps1 += __shfl_xor(ps1, m);
                ps2 += __shfl_xor(ps2, m); ps3 += __shfl_xor(ps3, m);
                pt0 += __shfl_xor(pt0, m); pt1 += __shfl_xor(pt1, m);
                pt2 += __shfl_xor(pt2, m); pt3 += __shfl_xor(pt3, m);
            }
            if (row < M && col < 4) {
                float vs = col == 0 ? ps0 : col == 1 ? ps1 : col == 2 ? ps2 : ps3;
                float vt = col == 0 ? pt0 : col == 1 ? pt1 : col == 2 ? pt2 : pt3;
                ssrc[(size_t)row * 4 + col] = vs;
                stgt[(size_t)row * 4 + col] = vt;
            }
        }
        return;
    }

    // ---------------- fp32 vector path ----------------
    const float* hin = (const float*)hin_;
    const float* W = (const float*)W_;
    const float* bias = (const float*)bias_;
    const float* a_src = (const float*)a_src_;
    const float* a_tgt = (const float*)a_tgt_;
    float* hp = (float*)hp_;
    const int t = threadIdx.x;
    const int row0 = blockIdx.x * 32;
    if (row0 >= M) return;

    for (int i = t; i < 32 * 64; i += 256) {
        int r = i >> 6, kk = (i & 63) * 2;
        int row = row0 + r;
        float2 v = (row < M) ? *(const float2*)(hin + (size_t)row * 128 + kk)
                             : make_float2(0.f, 0.f);
        hs[r][kk] = v.x; hs[r][kk + 1] = v.y;
    }
    __syncthreads();

    const int cg = (t & 31) * 4;
    const int rg = (t >> 5) * 4;
    float acc[4][4] = {};
    for (int k = 0; k < 128; k += 4) {
        float4 h0 = *(const float4*)&hs[rg + 0][k];
        float4 h1 = *(const float4*)&hs[rg + 1][k];
        float4 h2 = *(const float4*)&hs[rg + 2][k];
        float4 h3 = *(const float4*)&hs[rg + 3][k];
        #pragma unroll
        for (int j = 0; j < 4; j++) {
            float4 w4 = *(const float4*)(W + (size_t)(k + j) * 128 + cg);
            float hh0 = ((const float*)&h0)[j], hh1 = ((const float*)&h1)[j];
            float hh2 = ((const float*)&h2)[j], hh3 = ((const float*)&h3)[j];
            acc[0][0] += hh0 * w4.x; acc[0][1] += hh0 * w4.y; acc[0][2] += hh0 * w4.z; acc[0][3] += hh0 * w4.w;
            acc[1][0] += hh1 * w4.x; acc[1][1] += hh1 * w4.y; acc[1][2] += hh1 * w4.z; acc[1][3] += hh1 * w4.w;
            acc[2][0] += hh2 * w4.x; acc[2][1] += hh2 * w4.y; acc[2][2] += hh2 * w4.z; acc[2][3] += hh2 * w4.w;
            acc[3][0] += hh3 * w4.x; acc[3][1] += hh3 * w4.y; acc[3][2] += hh3 * w4.z; acc[3][3] += hh3 * w4.w;
        }
    }
    float b0 = bias[cg], b1 = bias[cg + 1], b2 = bias[cg + 2], b3 = bias[cg + 3];
    #pragma unroll
    for (int i = 0; i < 4; i++) {
        acc[i][0] += b0; acc[i][1] += b1; acc[i][2] += b2; acc[i][3] += b3;
    }
    #pragma unroll
    for (int i = 0; i < 4; i++) {
        int row = row0 + rg + i;
        if (row < M)
            *(float4*)(hp + (size_t)row * 128 + cg) =
                make_float4(acc[i][0], acc[i][1], acc[i][2], acc[i][3]);
    }
    const int head = cg >> 5;
    float as0 = a_src[cg], as1 = a_src[cg + 1], as2 = a_src[cg + 2], as3 = a_src[cg + 3];
    float at0 = a_tgt[cg], at1 = a_tgt[cg + 1], at2 = a_tgt[cg + 2], at3 = a_tgt[cg + 3];
    float p1[4], p2[4];
    #pragma unroll
    for (int i = 0; i < 4; i++) {
        p1[i] = acc[i][0] * as0 + acc[i][1] * as1 + acc[i][2] * as2 + acc[i][3] * as3;
        p2[i] = acc[i][0] * at0 + acc[i][1] * at1 + acc[i][2] * at2 + acc[i][3] * at3;
    }
    #pragma unroll
    for (int m = 1; m < 8; m <<= 1) {
        #pragma unroll
        for (int i = 0; i < 4; i++) {
            p1[i] += __shfl_xor(p1[i], m);
            p2[i] += __shfl_xor(p2[i], m);
        }
    }
    if ((t & 7) == 0) {
        #pragma unroll
        for (int i = 0; i < 4; i++) { sh_s[rg + i][head] = p1[i]; sh_t[rg + i][head] = p2[i]; }
    }
    __syncthreads();
    if (t < 128) {
        int r = t >> 2, h = t & 3;
        int row = row0 + r;
        if (row < M) ssrc[(size_t)row * 4 + h] = sh_s[r][h];
    } else {
        int r = (t - 128) >> 2, h = t & 3;
        int row = row0 + r;
        if (row < M) stgt[(size_t)row * 4 + h] = sh_t[r][h];
    }
}

// ---------------------------------------------------------------------------
// Histogram + rank.
// ---------------------------------------------------------------------------
__global__ __launch_bounds__(256) void k_hist(
    const void* __restrict__ eidx, const int* __restrict__ flags,
    int* __restrict__ cnt, int* __restrict__ rank, int n_edges, int n_nodes)
{
    int e = blockIdx.x * 256 + threadIdx.x;
    if (e >= n_edges) return;
    int t = get_i(eidx, (size_t)n_edges + e, flags[1]);
    t = min(max(t, 0), n_nodes - 1);
    rank[e] = atomicAdd(&cnt[t], 1);
}

// ---------------------------------------------------------------------------
// Scan phase 1.
// ---------------------------------------------------------------------------
__global__ __launch_bounds__(256) void k_scan1(
    const int* __restrict__ cnt, int* __restrict__ offs, int* __restrict__ bsum, int n)
{
    __shared__ int lds[256];
    const int t = threadIdx.x;
    const int idx = blockIdx.x * 1024 + t * 4;
    int v[4];
    #pragma unroll
    for (int j = 0; j < 4; j++) v[j] = (idx + j < n) ? cnt[idx + j] : 0;
    int s = v[0] + v[1] + v[2] + v[3];
    lds[t] = s;
    __syncthreads();
    #pragma unroll
    for (int off = 1; off < 256; off <<= 1) {
        int x = (t >= off) ? lds[t - off] : 0;
        __syncthreads();
        lds[t] += x;
        __syncthreads();
    }
    int run = lds[t] - s;
    #pragma unroll
    for (int j = 0; j < 4; j++) {
        if (idx + j < n) offs[idx + j] = run;
        run += v[j];
    }
    if (t == 255) bsum[blockIdx.x] = lds[255];
}

// ---------------------------------------------------------------------------
// Scan phase 2 (fused block-sum scan + add).
// ---------------------------------------------------------------------------
__global__ __launch_bounds__(256) void k_scan3(
    int* __restrict__ offs, const int* __restrict__ bsum, int n, int n_edges, int nb)
{
    __shared__ int lds[256];
    __shared__ int excl[256];
    const int t = threadIdx.x;
    int v = (t < nb) ? bsum[t] : 0;
    lds[t] = v;
    __syncthreads();
    #pragma unroll
    for (int off = 1; off < 256; off <<= 1) {
        int x = (t >= off) ? lds[t - off] : 0;
        __syncthreads();
        lds[t] += x;
        __syncthreads();
    }
    excl[t] = lds[t] - v;
    __syncthreads();
    const int add = excl[blockIdx.x];
    const int idx = blockIdx.x * 1024 + t * 4;
    #pragma unroll
    for (int j = 0; j < 4; j++)
        if (idx + j < n) offs[idx + j] += add;
    if (blockIdx.x == 0 && t == 0) offs[n] = n_edges;
}

// ---------------------------------------------------------------------------
// Scatter (no atomics).
// ---------------------------------------------------------------------------
__global__ __launch_bounds__(256) void k_scatter(
    const void* __restrict__ eidx, const int* __restrict__ flags,
    const int* __restrict__ offs, const int* __restrict__ rank,
    int* __restrict__ src_sorted, int n_edges, int n_nodes)
{
    int e = blockIdx.x * 256 + threadIdx.x;
    if (e >= n_edges) return;
    const int m64 = flags[1];
    int s = get_i(eidx, e, m64);
    int t = get_i(eidx, (size_t)n_edges + e, m64);
    s = min(max(s, 0), n_nodes - 1);
    t = min(max(t, 0), n_nodes - 1);
    src_sorted[offs[t] + rank[e]] = s;
}

// ---------------------------------------------------------------------------
// Aggregation: 4 INDEPENDENT nodes per wave — slot (lane>>4) owns node
// base+slot entirely: its own edge walk, uint4 gathers (x4 unroll = 16
// in flight per wave), no cross-slot reductions, no wasted remainder loads.
// hp is permuted bf16; un-permute via per-slot LDS bounce.
// ---------------------------------------------------------------------------
__global__ __launch_bounds__(256) void k_agg_csr(
    const int* __restrict__ offs, const int* __restrict__ src_sorted,
    const float* __restrict__ ssrc, const float* __restrict__ stgt,
    const void* __restrict__ hp, void* __restrict__ out,
    const int* __restrict__ flags, int n_nodes)
{
    const int fp32 = flags[0];
    const int wave = threadIdx.x >> 6;
    const int lane = threadIdx.x & 63;

    if (!fp32) {
        __shared__ u16 ob[4][512];
        const int slot = lane >> 4;
        const int li = lane & 15;
        const int nid = blockIdx.x * 16 + wave * 4 + slot;
        if (nid >= n_nodes) return;

        const u16* hpb = (const u16*)hp;
        const float4* ssrc4 = (const float4*)ssrc;
        const float4 st4 = ((const float4*)stgt)[nid];
        const int d0 = offs[nid], d1 = offs[nid + 1];

        float a[8] = {};
        float4 es = make_float4(0.f, 0.f, 0.f, 0.f);

        auto edge_w = [&](int s) -> float4 {
            float4 cs = ssrc4[s];
            return make_float4(__expf(lrelu_clamp(cs.x + st4.x)),
                               __expf(lrelu_clamp(cs.y + st4.y)),
                               __expf(lrelu_clamp(cs.z + st4.z)),
                               __expf(lrelu_clamp(cs.w + st4.w)));
        };
        auto accum = [&](float4 w, uint4 v) {
            a[0] += w.x * bf2f((u16)(v.x & 0xffff));
            a[1] += w.x * bf2f((u16)(v.x >> 16));
            a[2] += w.y * bf2f((u16)(v.y & 0xffff));
            a[3] += w.y * bf2f((u16)(v.y >> 16));
            a[4] += w.z * bf2f((u16)(v.z & 0xffff));
            a[5] += w.z * bf2f((u16)(v.z >> 16));
            a[6] += w.w * bf2f((u16)(v.w & 0xffff));
            a[7] += w.w * bf2f((u16)(v.w >> 16));
            es.x += w.x; es.y += w.y; es.z += w.z; es.w += w.w;
        };

        int e = d0;
        for (; e + 4 <= d1; e += 4) {
            int s0 = src_sorted[e + 0], s1 = src_sorted[e + 1];
            int s2 = src_sorted[e + 2], s3 = src_sorted[e + 3];
            uint4 v0 = *(const uint4*)(hpb + (size_t)s0 * 128 + li * 8);
            uint4 v1 = *(const uint4*)(hpb + (size_t)s1 * 128 + li * 8);
            uint4 v2 = *(const uint4*)(hpb + (size_t)s2 * 128 + li * 8);
            uint4 v3 = *(const uint4*)(hpb + (size_t)s3 * 128 + li * 8);
            float4 w0 = edge_w(s0), w1 = edge_w(s1), w2 = edge_w(s2), w3 = edge_w(s3);
            accum(w0, v0); accum(w1, v1); accum(w2, v2); accum(w3, v3);
        }
        for (; e < d1; e++) {
            int s = src_sorted[e];
            uint4 v = *(const uint4*)(hpb + (size_t)s * 128 + li * 8);
            accum(edge_w(s), v);
        }

        float inv[4] = {1.f / (es.x + 1e-16f), 1.f / (es.y + 1e-16f),
                        1.f / (es.z + 1e-16f), 1.f / (es.w + 1e-16f)};
        #pragma unroll
        for (int m = 0; m < 8; m++)
            ob[wave][slot * 128 + m * 16 + li] = f2bf(a[m] * inv[m >> 1]);
        uint4 ov = *(const uint4*)&ob[wave][slot * 128 + li * 8];
        *(uint4*)((u16*)out + (size_t)nid * 128 + li * 8) = ov;
    } else {
        // fp32 fallback: wave processes its 4 nodes sequentially, 64 lanes x
        // float2 per row, unroll 2.
        const float* hpf = (const float*)hp;
        for (int j = 0; j < 4; j++) {
            int nid = blockIdx.x * 16 + wave * 4 + j;
            if (nid >= n_nodes) break;
            const int head = lane >> 4;
            const int d0 = offs[nid], d1 = offs[nid + 1];
            const float st = stgt[(size_t)nid * 4 + head];
            float ax = 0.f, ay = 0.f, es = 0.f;
            int e = d0;
            for (; e + 2 <= d1; e += 2) {
                int s0 = src_sorted[e], s1 = src_sorted[e + 1];
                float c0 = ssrc[(size_t)s0 * 4 + head];
                float c1 = ssrc[(size_t)s1 * 4 + head];
                float2 h0 = *(const float2*)(hpf + (size_t)s0 * 128 + lane * 2);
                float2 h1 = *(const float2*)(hpf + (size_t)s1 * 128 + lane * 2);
                float w0 = __expf(lrelu_clamp(c0 + st));
                float w1 = __expf(lrelu_clamp(c1 + st));
                ax += w0 * h0.x + w1 * h1.x;
                ay += w0 * h0.y + w1 * h1.y;
                es += w0 + w1;
            }
            for (; e < d1; e++) {
                int s = src_sorted[e];
                float c = ssrc[(size_t)s * 4 + head];
                float2 hv = *(const float2*)(hpf + (size_t)s * 128 + lane * 2);
                float w = __expf(lrelu_clamp(c + st));
                ax += w * hv.x; ay += w * hv.y; es += w;
            }
            float inv = 1.0f / (es + 1e-16f);
            *(float2*)((float*)out + (size_t)nid * 128 + lane * 2) =
                make_float2(ax * inv, ay * inv);
        }
    }
}

extern "C" void kernel_launch(void* const* d_in, const int* in_sizes, int n_in,
                              void* d_out, int out_size, void* d_ws, size_t ws_size,
                              hipStream_t stream)
{
    const void* h_in  = d_in[0];
    const void* eidx  = d_in[1];
    const void* W     = d_in[2];
    const void* bias  = d_in[3];
    const void* a_src = d_in[4];
    const void* a_tgt = d_in[5];

    const int n_nodes = in_sizes[0] / 128;
    const int n_edges = in_sizes[1] / 2;
    const int nb = (n_nodes + 1023) / 1024;   // <= 256

    char* p = (char*)d_ws;
    auto alloc = [&](size_t bytes) { char* q = p; p += (bytes + 255) & ~(size_t)255; return q; };
    int*   flags      = (int*)  alloc(256);
    void*  hp         = (void*) alloc((size_t)n_nodes * 128 * sizeof(float)); // fp32 worst case
    u16*   Wt         = (u16*)  alloc(128 * 128 * sizeof(u16));
    float* ssrc       = (float*)alloc((size_t)n_nodes * 4 * sizeof(float));
    float* stgt       = (float*)alloc((size_t)n_nodes * 4 * sizeof(float));
    int*   cnt        = (int*)  alloc((size_t)n_nodes * sizeof(int));
    int*   offs       = (int*)  alloc(((size_t)n_nodes + 1) * sizeof(int));
    int*   bsum       = (int*)  alloc(256 * sizeof(int));
    int*   rank       = (int*)  alloc((size_t)n_edges * sizeof(int));
    int*   src_sorted = (int*)  alloc((size_t)n_edges * sizeof(int));

    k_init   <<<65, 256, 0, stream>>>((const u16*)h_in, (const int*)eidx, flags,
                                      (const u16*)W, Wt, cnt, n_nodes);
    k_proj   <<<(n_nodes + 31) / 32, 256, 0, stream>>>(h_in, W, Wt, bias, a_src, a_tgt,
                                                       flags, hp, ssrc, stgt, n_nodes);
    k_hist   <<<(n_edges + 255) / 256, 256, 0, stream>>>(eidx, flags, cnt, rank, n_edges, n_nodes);
    k_scan1  <<<nb, 256, 0, stream>>>(cnt, offs, bsum, n_nodes);
    k_scan3  <<<nb, 256, 0, stream>>>(offs, bsum, n_nodes, n_edges, nb);
    k_scatter<<<(n_edges + 255) / 256, 256, 0, stream>>>(eidx, flags, offs, rank,
                                                         src_sorted, n_edges, n_nodes);
    k_agg_csr<<<(n_nodes + 15) / 16, 256, 0, stream>>>(offs, src_sorted, ssrc, stgt,
                                                       hp, d_out, flags, n_nodes);
}